// Round 13
// baseline (290.780 us; speedup 1.0000x reference)
//
#include <hip/hip_runtime.h>
#include <hip/hip_bf16.h>

#define D 128
#define EPS 1e-5f
#define CHK 8192            // edges per phase-1 chunk
#define P2CAP 6144          // max edges per 256-dst bucket

typedef __attribute__((ext_vector_type(8))) short short8;
typedef __attribute__((ext_vector_type(4))) float float4v;

#define AS1 __attribute__((address_space(1)))
#define AS3 __attribute__((address_space(3)))

__device__ inline ushort f2bf(float f) {
    __hip_bfloat16 b = __float2bfloat16(f);
    return *reinterpret_cast<ushort*>(&b);
}
__device__ inline float bf_lo(uint u) { return __uint_as_float(u << 16); }
__device__ inline float bf_hi(uint u) { return __uint_as_float(u & 0xffff0000u); }

// ---------- K1: weight-convert (blocks 0..12) + chunk-hist (fused k_c1,
// blocks 13..13+C-1) + LN1+ReLU (all blocks >= 13) -------------------------
__global__ void k_ln1cvt(const float* __restrict__ x, const int* __restrict__ ntp,
                         const float* __restrict__ gamma, const float* __restrict__ beta,
                         ushort* __restrict__ y,
                         const float* __restrict__ Wrel, const float* __restrict__ Wroot,
                         const float* __restrict__ Wmlp, ushort* __restrict__ Wt,
                         const int* __restrict__ edst, int* __restrict__ hist,
                         int N, int E, int C, int B) {
    __shared__ ushort t[128][136];
    __shared__ int cnt[256];
    if (blockIdx.x < 13) {
        int m = blockIdx.x;
        const float* src = (m == 0) ? Wroot
                         : (m <= 8) ? Wrel + (size_t)(m - 1) * D * D
                                    : Wmlp + (size_t)(m - 9) * D * D;
        for (int i = threadIdx.x; i < D * D; i += 256) {
            int k = i >> 7, n = i & 127;
            t[n][k] = f2bf(src[i]);
        }
        __syncthreads();
        ushort* dst = Wt + (size_t)m * D * D;
        for (int i = threadIdx.x; i < D * D; i += 256) {
            int frag = i >> 9;
            int lane = (i >> 3) & 63;
            int j = i & 7;
            int nt = frag >> 2, ks = frag & 3;
            int n = nt * 16 + (lane & 15);
            int k = ks * 32 + (lane >> 4) * 8 + j;
            dst[i] = t[n][k];
        }
        return;
    }
    // fused c1: chunk histogram (block 13+c handles chunk c; branch is
    // blockIdx-uniform so the barriers are legal)
    int c = blockIdx.x - 13;
    if (c < C) {
        int tid = threadIdx.x;
        cnt[tid] = 0;
        __syncthreads();
        #pragma unroll 4
        for (int k = 0; k < CHK / 256; ++k) {
            int e = c * CHK + k * 256 + tid;
            if (e < E) atomicAdd(&cnt[edst[e] >> 8], 1);
        }
        __syncthreads();
        if (tid < B) hist[c * B + tid] = cnt[tid];
    }
    int n = (blockIdx.x - 13) * 4 + (threadIdx.x >> 6);
    if (n >= N) return;
    int l = threadIdx.x & 63;
    float2 v = *(const float2*)(x + (size_t)n * D + 2 * l);
    float s = v.x + v.y, s2 = v.x * v.x + v.y * v.y;
    #pragma unroll
    for (int o = 32; o; o >>= 1) { s += __shfl_xor(s, o, 64); s2 += __shfl_xor(s2, o, 64); }
    float mu = s * (1.0f / D);
    float var = s2 * (1.0f / D) - mu * mu;
    float inv = rsqrtf(var + EPS);
    int tt = ntp[n];
    float2 g = *(const float2*)(gamma + tt * D + 2 * l);
    float2 b = *(const float2*)(beta + tt * D + 2 * l);
    float a0 = fmaxf((v.x - mu) * inv * g.x + b.x, 0.0f);
    float a1 = fmaxf((v.y - mu) * inv * g.y + b.y, 0.0f);
    ((uint*)(y + (size_t)n * D))[l] = ((uint)f2bf(a1) << 16) | f2bf(a0);
}

// ---------- edge sort by dst (R13: k_c2 eliminated; p1s/p2 derive from hist) --
// p1s: block c scatters chunk c. Thread tid owns bucket tid: derives bucket
// total (sum over all chunks) and this chunk's offset (sum over chunks < c)
// straight from hist (L2-hot, 77KB), then the usual in-block scan gives the
// block-owned write base. Bit-identical arithmetic to the old c2+p1s pair.
__global__ void k_p1s(const int* __restrict__ edst, const int* __restrict__ esrc,
                      const int* __restrict__ etyp, const int* __restrict__ hist,
                      uint* __restrict__ edata, int E, int B, int C) {
    __shared__ int ps[256];
    __shared__ int base[256];
    __shared__ int cnt[256];
    int c = blockIdx.x, tid = threadIdx.x;
    int tot = 0, myoff = 0;
    if (tid < B) {
        for (int cc = 0; cc < C; ++cc) {
            int h = hist[cc * B + tid];
            tot += h;
            if (cc < c) myoff += h;
        }
    }
    ps[tid] = tot;
    __syncthreads();
    for (int o = 1; o < 256; o <<= 1) {
        int v = (tid >= o) ? ps[tid - o] : 0;
        __syncthreads();
        ps[tid] += v;
        __syncthreads();
    }
    base[tid] = (ps[tid] - tot) + myoff;
    cnt[tid] = 0;
    __syncthreads();
    #pragma unroll 4
    for (int k = 0; k < CHK / 256; ++k) {
        int e = c * CHK + k * 256 + tid;
        if (e < E) {
            int d = edst[e];
            int b = d >> 8;
            int r = atomicAdd(&cnt[b], 1);
            edata[base[b] + r] =
                ((uint)esrc[e] << 12) | ((uint)(d & 255) << 4) | (uint)etyp[e];
        }
    }
}
// p2: exact counting-sort within each 256-dst bucket; bucket totals derived
// from hist; j0 = exclusive prefix = ps[b-1] (inclusive scan).
__global__ void k_p2(const uint* __restrict__ edata, const int* __restrict__ hist,
                     uint* __restrict__ epack, int* __restrict__ offs,
                     int N, int E, int B, int C) {
    __shared__ int ps[256];
    __shared__ uint ed[P2CAP];
    __shared__ int cnt[256], off[256], cur[256];
    int b = blockIdx.x, tid = threadIdx.x;
    int tot = 0;
    if (tid < B)
        for (int cc = 0; cc < C; ++cc) tot += hist[cc * B + tid];
    ps[tid] = tot;
    __syncthreads();
    for (int o = 1; o < 256; o <<= 1) {
        int v = (tid >= o) ? ps[tid - o] : 0;
        __syncthreads();
        ps[tid] += v;
        __syncthreads();
    }
    int j0 = (b == 0) ? 0 : ps[b - 1];             // exclusive prefix of bucket b
    int count = ps[b] - j0;
    if (count > P2CAP) count = P2CAP;
    for (int i = tid; i < count; i += 256) ed[i] = edata[j0 + i];
    cnt[tid] = 0;
    __syncthreads();
    for (int i = tid; i < count; i += 256) atomicAdd(&cnt[(ed[i] >> 4) & 255], 1);
    __syncthreads();
    if (tid == 0) {
        int s = 0;
        for (int i = 0; i < 256; ++i) { off[i] = s; cur[i] = s; s += cnt[i]; }
    }
    __syncthreads();
    for (int i = tid; i < count; i += 256) {
        uint v = ed[i];
        int dl = (v >> 4) & 255;
        int r = atomicAdd(&cur[dl], 1);
        epack[j0 + r] = ((v & 15u) << 28) | (v >> 12);
    }
    int v = b * 256 + tid;
    if (v < N) offs[v] = j0 + off[tid];
    if (b == 0 && tid == 0) offs[N] = E;
}

// ---------- K3: z[v][r] = sum of y[src] over edges (dst=v, type=r) ------------
// R7 form (proven): coalesced 64-edge chunk load + shfl broadcast + 4-deep
// row gathers. (R11 switch-free = 94.7us serialized; R10 in-GEMM = 379us.)
__global__ void k_zagg(const ushort* __restrict__ ybuf, const int* __restrict__ offs,
                       const uint* __restrict__ epack, ushort* __restrict__ zbuf, int N) {
    int wave = threadIdx.x >> 6;
    int l = threadIdx.x & 63;
    int v = blockIdx.x * 4 + wave;
    if (v >= N) return;
    float2 a0 = {0.f,0.f}, a1 = {0.f,0.f}, a2 = {0.f,0.f}, a3 = {0.f,0.f};
    float2 a4 = {0.f,0.f}, a5 = {0.f,0.f}, a6 = {0.f,0.f}, a7 = {0.f,0.f};
    const uint* yb = (const uint*)ybuf;
    int j = offs[v], e1 = offs[v + 1];

#define ZACC(P, U) do {                                                   \
        float lo = bf_lo(U), hi = bf_hi(U);                               \
        switch ((P) >> 28) {                                              \
            case 0: a0.x += lo; a0.y += hi; break;                        \
            case 1: a1.x += lo; a1.y += hi; break;                        \
            case 2: a2.x += lo; a2.y += hi; break;                        \
            case 3: a3.x += lo; a3.y += hi; break;                        \
            case 4: a4.x += lo; a4.y += hi; break;                        \
            case 5: a5.x += lo; a5.y += hi; break;                        \
            case 6: a6.x += lo; a6.y += hi; break;                        \
            default: a7.x += lo; a7.y += hi; break;                       \
        }                                                                 \
    } while (0)

    while (j < e1) {
        int chunk = min(64, e1 - j);
        uint pl = (j + l < e1) ? epack[j + l] : 0;
        int i = 0;
        for (; i + 3 < chunk; i += 4) {
            uint p0 = __shfl(pl, i, 64);
            uint p1 = __shfl(pl, i + 1, 64);
            uint p2 = __shfl(pl, i + 2, 64);
            uint p3 = __shfl(pl, i + 3, 64);
            uint u0 = yb[(size_t)(p0 & 0x0FFFFFFFu) * 64 + l];
            uint u1 = yb[(size_t)(p1 & 0x0FFFFFFFu) * 64 + l];
            uint u2 = yb[(size_t)(p2 & 0x0FFFFFFFu) * 64 + l];
            uint u3 = yb[(size_t)(p3 & 0x0FFFFFFFu) * 64 + l];
            ZACC(p0, u0); ZACC(p1, u1); ZACC(p2, u2); ZACC(p3, u3);
        }
        for (; i < chunk; ++i) {
            uint p = __shfl(pl, i, 64);
            uint u = yb[(size_t)(p & 0x0FFFFFFFu) * 64 + l];
            ZACC(p, u);
        }
        j += chunk;
    }
#undef ZACC
    uint* zrow = (uint*)(zbuf + (size_t)v * 1024);
    zrow[0 * 64 + l] = ((uint)f2bf(a0.y) << 16) | f2bf(a0.x);
    zrow[1 * 64 + l] = ((uint)f2bf(a1.y) << 16) | f2bf(a1.x);
    zrow[2 * 64 + l] = ((uint)f2bf(a2.y) << 16) | f2bf(a2.x);
    zrow[3 * 64 + l] = ((uint)f2bf(a3.y) << 16) | f2bf(a3.x);
    zrow[4 * 64 + l] = ((uint)f2bf(a4.y) << 16) | f2bf(a4.x);
    zrow[5 * 64 + l] = ((uint)f2bf(a5.y) << 16) | f2bf(a5.x);
    zrow[6 * 64 + l] = ((uint)f2bf(a6.y) << 16) | f2bf(a6.x);
    zrow[7 * 64 + l] = ((uint)f2bf(a7.y) << 16) | f2bf(a7.x);
}

// ---------- K4: LDS-staged conv-GEMM (K=1152) + LN2 + ReLU + MLP --------------
// R7 form verbatim (65us, occ 23%): 32KB LDS, y2-overlay on bsm[1], zbuf input.
__device__ __forceinline__ void gl_lds16(const void* g, void* l) {
    __builtin_amdgcn_global_load_lds((const AS1 void*)g, (AS3 void*)l, 16, 0, 0);
}
__device__ __forceinline__ void stage_half(const ushort* __restrict__ Wt, int q,
                                           ushort* bsm0, int wave, int lane) {
    const char* g = (const char*)Wt + (size_t)q * 16384 + lane * 16;
    char* l = (char*)bsm0 + (q & 1) * 16384;
    #pragma unroll
    for (int i = 0; i < 4; ++i) {
        int c = i * 4 + wave;
        gl_lds16(g + c * 1024, l + c * 1024);
    }
}
__device__ __forceinline__ void stage_mlp_slice(const ushort* __restrict__ Wt, int nt,
                                                ushort* bsm0, int wave, int lane) {
    const char* g = (const char*)Wt + (size_t)(9 + wave) * 32768 + nt * 4096 + lane * 16;
    char* l = (char*)bsm0 + (nt & 1) * 16384 + wave * 4096;
    #pragma unroll
    for (int i = 0; i < 4; ++i)
        gl_lds16(g + i * 1024, l + i * 1024);
}
__device__ __forceinline__ void aloadG(short8 (&d)[4], const ushort* p, int off, int ao) {
    #pragma unroll
    for (int ks = 0; ks < 4; ++ks)
        d[ks] = *(const short8*)(p + off + ks * 32 + ao);
}
__device__ __forceinline__ void convHalf(float4v (&acc)[8], const short8 (&a)[4],
                                         const ushort* bsm_h, int h, int lane) {
    #pragma unroll
    for (int nt4 = 0; nt4 < 4; ++nt4) {
        #pragma unroll
        for (int ks = 0; ks < 4; ++ks) {
            short8 b = *(const short8*)(bsm_h + (((nt4 * 4 + ks) * 64 + lane) << 3));
            acc[h * 4 + nt4] = __builtin_amdgcn_mfma_f32_16x16x32_bf16(
                a[ks], b, acc[h * 4 + nt4], 0, 0, 0);
        }
    }
}

__launch_bounds__(256, 4)
__global__ void k_gm(const ushort* __restrict__ ybuf, const ushort* __restrict__ zbuf,
                     const ushort* __restrict__ Wt, const float* __restrict__ x,
                     const int* __restrict__ ntp,
                     const float* __restrict__ gamma, const float* __restrict__ beta,
                     const float* __restrict__ bmlp, float* __restrict__ out, int N) {
    __shared__ ushort bsm[2][8192];      // 2 x 16KB ping-pong; bsm[1] doubles as y2 overlay
    ushort* bsm0 = &bsm[0][0];
    int tid = threadIdx.x;
    int wave = tid >> 6, lane = tid & 63;
    int quad = lane >> 4, l15 = lane & 15;
    int ao = quad * 8;
    int base = blockIdx.x * 64 + wave * 16;             // 16 rows per wave

    const ushort* yrow = ybuf + (size_t)min(base + l15, N - 1) * 128;
    const ushort* zrow = zbuf + (size_t)min(base + l15, N - 1) * 1024;

    float4v acc[8];
    #pragma unroll
    for (int nt = 0; nt < 8; ++nt) acc[nt] = (float4v){0.f, 0.f, 0.f, 0.f};

    short8 aC[4], aN[4];
    stage_half(Wt, 0, bsm0, wave, lane);
    aloadG(aC, yrow, 0, ao);
    __syncthreads();

    #pragma unroll
    for (int m = 0; m < 9; ++m) {
        short8 (&cur)[4] = (m & 1) ? aN : aC;           // holds A[m]
        short8 (&nxt)[4] = (m & 1) ? aC : aN;
        stage_half(Wt, 2 * m + 1, bsm0, wave, lane);
        if (m < 8) aloadG(nxt, zrow, m * 128, ao);      // A[m+1] = z slot m
        convHalf(acc, cur, bsm0, 0, lane);
        __syncthreads();
        if (m < 8) stage_half(Wt, 2 * m + 2, bsm0, wave, lane);
        else       stage_mlp_slice(Wt, 0, bsm0, wave, lane);
        convHalf(acc, cur, bsm0 + 8192, 1, lane);
        __syncthreads();
    }

    ushort* yov = bsm0 + 8192 + wave * 2048;
    int ty[4];
    {
        float s[4] = {0.f, 0.f, 0.f, 0.f}, s2[4] = {0.f, 0.f, 0.f, 0.f};
        #pragma unroll
        for (int nt = 0; nt < 8; ++nt) {
            int col = nt * 16 + l15;
            #pragma unroll
            for (int r = 0; r < 4; ++r) {
                int row = base + quad * 4 + r;
                float xv = (row < N) ? x[(size_t)row * D + col] : 0.f;
                float t = acc[nt][r] + xv;
                acc[nt][r] = t;
                s[r] += t; s2[r] += t * t;
            }
        }
        #pragma unroll
        for (int r = 0; r < 4; ++r) {
            #pragma unroll
            for (int o = 1; o < 16; o <<= 1) {
                s[r]  += __shfl_xor(s[r],  o, 64);
                s2[r] += __shfl_xor(s2[r], o, 64);
            }
        }
        #pragma unroll
        for (int r = 0; r < 4; ++r) {
            int rc = min(base + quad * 4 + r, N - 1);
            ty[r] = ntp[rc];
            float mu  = s[r] * (1.0f / D);
            float var = s2[r] * (1.0f / D) - mu * mu;
            float inv = rsqrtf(var + EPS);
            int lrow = quad * 4 + r;
            #pragma unroll
            for (int nt = 0; nt < 8; ++nt) {
                int col = nt * 16 + l15;
                float yn = fmaxf((acc[nt][r] - mu) * inv * gamma[ty[r] * D + col]
                                 + beta[ty[r] * D + col], 0.f);
                yov[lrow * 128 + col] = f2bf(yn);
            }
        }
    }
    short8 a2[4];
    {
        const ushort* myrow = yov + l15 * 128;
        #pragma unroll
        for (int ks = 0; ks < 4; ++ks) a2[ks] = *(const short8*)(myrow + ks * 32 + ao);
    }
    __syncthreads();    // a2 settled before slice-1 staging clobbers overlay

    #pragma unroll
    for (int nt = 0; nt < 8; ++nt) {
        if (nt < 7) stage_mlp_slice(Wt, nt + 1, bsm0, wave, lane);
        const ushort* bh = bsm0 + (nt & 1) * 8192;
        float4v c0 = {0.f,0.f,0.f,0.f}, c1 = {0.f,0.f,0.f,0.f};
        float4v c2 = {0.f,0.f,0.f,0.f}, c3 = {0.f,0.f,0.f,0.f};
        #pragma unroll
        for (int ks = 0; ks < 4; ++ks) {
            int fo = (ks * 64 + lane) << 3;
            short8 b0 = *(const short8*)(bh + 0 * 2048 + fo);
            short8 b1 = *(const short8*)(bh + 1 * 2048 + fo);
            short8 b2 = *(const short8*)(bh + 2 * 2048 + fo);
            short8 b3 = *(const short8*)(bh + 3 * 2048 + fo);
            c0 = __builtin_amdgcn_mfma_f32_16x16x32_bf16(a2[ks], b0, c0, 0, 0, 0);
            c1 = __builtin_amdgcn_mfma_f32_16x16x32_bf16(a2[ks], b1, c1, 0, 0, 0);
            c2 = __builtin_amdgcn_mfma_f32_16x16x32_bf16(a2[ks], b2, c2, 0, 0, 0);
            c3 = __builtin_amdgcn_mfma_f32_16x16x32_bf16(a2[ks], b3, c3, 0, 0, 0);
        }
        int col = nt * 16 + l15;
        #pragma unroll
        for (int r = 0; r < 4; ++r) {
            int row = base + quad * 4 + r;
            if (row < N) {
                int t = ty[r];
                float v = (t == 0) ? c0[r] : (t == 1) ? c1[r] : (t == 2) ? c2[r] : c3[r];
                out[(size_t)row * D + col] = acc[nt][r] + v + bmlp[t * D + col];
            }
        }
        if (nt < 7) __syncthreads();
    }
}

// ---------- launch ------------------------------------------------------------
extern "C" void kernel_launch(void* const* d_in, const int* in_sizes, int n_in,
                              void* d_out, int out_size, void* d_ws, size_t ws_size,
                              hipStream_t stream) {
    const float* x          = (const float*)d_in[0];
    const int*   esrc       = (const int*)d_in[1];
    const int*   edst       = (const int*)d_in[2];
    const int*   ntyp       = (const int*)d_in[3];
    const int*   etyp       = (const int*)d_in[4];
    const float* conv_gamma = (const float*)d_in[5];
    const float* conv_beta  = (const float*)d_in[6];
    const float* W_rel      = (const float*)d_in[7];
    const float* W_root     = (const float*)d_in[8];
    const float* mlp_gamma  = (const float*)d_in[9];
    const float* mlp_beta   = (const float*)d_in[10];
    const float* W_mlp      = (const float*)d_in[11];
    const float* b_mlp      = (const float*)d_in[12];
    float* out = (float*)d_out;

    int N = in_sizes[0] / D;
    int E = in_sizes[1];
    int C = (E + CHK - 1) / CHK;        // chunks (<=128)
    int B = (N + 255) / 256;            // coarse buckets (<=256)

    char* p = (char*)d_ws;
    auto take = [&p](size_t bytes) { char* q = p; p += (bytes + 255) & ~(size_t)255; return q; };
    ushort* ybuf    = (ushort*)take((size_t)N * D * 2);
    ushort* zbuf    = (ushort*)take((size_t)N * 1024 * 2);
    ushort* Wt      = (ushort*)take((size_t)13 * D * D * 2);
    uint*   edata   = (uint*)take((size_t)E * 4);
    uint*   epack   = (uint*)take((size_t)E * 4);
    int*    offs    = (int*)take((size_t)(N + 1) * 4);
    int*    hist    = (int*)take((size_t)C * B * 4);

    // K1: weights + LN1 + fused chunk-hist
    k_ln1cvt<<<13 + (N + 3) / 4, 256, 0, stream>>>(x, ntyp, conv_gamma, conv_beta,
                                                   ybuf, W_rel, W_root, W_mlp, Wt,
                                                   edst, hist, N, E, C, B);

    // R13: k_c2 eliminated -- p1s/p2 derive bucket bases from hist directly
    k_p1s<<<C, 256, 0, stream>>>(edst, esrc, etyp, hist, edata, E, B, C);
    k_p2<<<B, 256, 0, stream>>>(edata, hist, epack, offs, N, E, B, C);

    k_zagg<<<(N + 3) / 4, 256, 0, stream>>>(ybuf, offs, epack, zbuf, N);

    k_gm<<<(N + 63) / 64, 256, 0, stream>>>(ybuf, zbuf, Wt, x, ntyp,
                                            mlp_gamma, mlp_beta, b_mlp, out, N);
}

// Round 14
// 253.131 us; speedup vs baseline: 1.1487x; 1.1487x over previous
//
#include <hip/hip_runtime.h>
#include <hip/hip_bf16.h>

#define D 128
#define EPS 1e-5f
#define CHK 8192            // edges per phase-1 chunk
#define P2CAP 6144          // max edges per 256-dst bucket

typedef __attribute__((ext_vector_type(8))) short short8;
typedef __attribute__((ext_vector_type(4))) float float4v;

#define AS1 __attribute__((address_space(1)))
#define AS3 __attribute__((address_space(3)))

__device__ inline ushort f2bf(float f) {
    __hip_bfloat16 b = __float2bfloat16(f);
    return *reinterpret_cast<ushort*>(&b);
}
__device__ inline float bf_lo(uint u) { return __uint_as_float(u << 16); }
__device__ inline float bf_hi(uint u) { return __uint_as_float(u & 0xffff0000u); }

// ---------- K1: weight-convert (blocks 0..12) + chunk-hist (fused k_c1,
// blocks 13..13+C-1) + LN1+ReLU (all blocks >= 13) -------------------------
__global__ void k_ln1cvt(const float* __restrict__ x, const int* __restrict__ ntp,
                         const float* __restrict__ gamma, const float* __restrict__ beta,
                         ushort* __restrict__ y,
                         const float* __restrict__ Wrel, const float* __restrict__ Wroot,
                         const float* __restrict__ Wmlp, ushort* __restrict__ Wt,
                         const int* __restrict__ edst, int* __restrict__ hist,
                         int N, int E, int C, int B) {
    __shared__ ushort t[128][136];
    __shared__ int cnt[256];
    if (blockIdx.x < 13) {
        int m = blockIdx.x;
        const float* src = (m == 0) ? Wroot
                         : (m <= 8) ? Wrel + (size_t)(m - 1) * D * D
                                    : Wmlp + (size_t)(m - 9) * D * D;
        for (int i = threadIdx.x; i < D * D; i += 256) {
            int k = i >> 7, n = i & 127;
            t[n][k] = f2bf(src[i]);
        }
        __syncthreads();
        ushort* dst = Wt + (size_t)m * D * D;
        for (int i = threadIdx.x; i < D * D; i += 256) {
            int frag = i >> 9;
            int lane = (i >> 3) & 63;
            int j = i & 7;
            int nt = frag >> 2, ks = frag & 3;
            int n = nt * 16 + (lane & 15);
            int k = ks * 32 + (lane >> 4) * 8 + j;
            dst[i] = t[n][k];
        }
        return;
    }
    // fused c1: chunk histogram (block 13+c handles chunk c; branch is
    // blockIdx-uniform so the barriers are legal)
    int c = blockIdx.x - 13;
    if (c < C) {
        int tid = threadIdx.x;
        cnt[tid] = 0;
        __syncthreads();
        #pragma unroll 4
        for (int k = 0; k < CHK / 256; ++k) {
            int e = c * CHK + k * 256 + tid;
            if (e < E) atomicAdd(&cnt[edst[e] >> 8], 1);
        }
        __syncthreads();
        if (tid < B) hist[c * B + tid] = cnt[tid];
    }
    int n = (blockIdx.x - 13) * 4 + (threadIdx.x >> 6);
    if (n >= N) return;
    int l = threadIdx.x & 63;
    float2 v = *(const float2*)(x + (size_t)n * D + 2 * l);
    float s = v.x + v.y, s2 = v.x * v.x + v.y * v.y;
    #pragma unroll
    for (int o = 32; o; o >>= 1) { s += __shfl_xor(s, o, 64); s2 += __shfl_xor(s2, o, 64); }
    float mu = s * (1.0f / D);
    float var = s2 * (1.0f / D) - mu * mu;
    float inv = rsqrtf(var + EPS);
    int tt = ntp[n];
    float2 g = *(const float2*)(gamma + tt * D + 2 * l);
    float2 b = *(const float2*)(beta + tt * D + 2 * l);
    float a0 = fmaxf((v.x - mu) * inv * g.x + b.x, 0.0f);
    float a1 = fmaxf((v.y - mu) * inv * g.y + b.y, 0.0f);
    ((uint*)(y + (size_t)n * D))[l] = ((uint)f2bf(a1) << 16) | f2bf(a0);
}

// ---------- two-phase edge sort by dst (R14: k_c2 restored -- R13's in-kernel
// hist re-derivation was 98 serial global loads/thread with 98-block TLP,
// +28us; parallel-launch bookkeeping is cheaper) ------------------------------
__global__ void k_c2(const int* __restrict__ hist, int* __restrict__ chunkoff,
                     int* __restrict__ bucktot, int C, int B) {
    __shared__ int v[128];
    int b = blockIdx.x, t = threadIdx.x;
    v[t] = (t < C) ? hist[t * B + b] : 0;
    __syncthreads();
    if (t == 0) {
        int s = 0;
        for (int c = 0; c < C; ++c) { int x = v[c]; v[c] = s; s += x; }
        bucktot[b] = s;
    }
    __syncthreads();
    if (t < C) chunkoff[t * B + b] = v[t];
}
// p1s: scatter edges into bucket-major edata; in-block scan of bucktot -> base
__global__ void k_p1s(const int* __restrict__ edst, const int* __restrict__ esrc,
                      const int* __restrict__ etyp, const int* __restrict__ bucktot,
                      const int* __restrict__ chunkoff, uint* __restrict__ edata,
                      int E, int B) {
    __shared__ int ps[256];
    __shared__ int base[256];
    __shared__ int cnt[256];
    int c = blockIdx.x, tid = threadIdx.x;
    int bt = (tid < B) ? bucktot[tid] : 0;
    ps[tid] = bt;
    __syncthreads();
    for (int o = 1; o < 256; o <<= 1) {
        int v = (tid >= o) ? ps[tid - o] : 0;
        __syncthreads();
        ps[tid] += v;
        __syncthreads();
    }
    base[tid] = (ps[tid] - bt) + ((tid < B) ? chunkoff[c * B + tid] : 0);
    cnt[tid] = 0;
    __syncthreads();
    #pragma unroll 4
    for (int k = 0; k < CHK / 256; ++k) {
        int e = c * CHK + k * 256 + tid;
        if (e < E) {
            int d = edst[e];
            int b = d >> 8;
            int r = atomicAdd(&cnt[b], 1);
            edata[base[b] + r] =
                ((uint)esrc[e] << 12) | ((uint)(d & 255) << 4) | (uint)etyp[e];
        }
    }
}
// p2: exact counting-sort within each 256-dst bucket; in-block scan for j0.
// R14 micro-fix: the tid==0 serial 256-iteration prefix loop (wall ~3-4us,
// since all 196 blocks run it concurrently) replaced by the same parallel
// in-block scan already used for bucket totals (ps[] reused after j0).
__global__ void k_p2(const uint* __restrict__ edata, const int* __restrict__ bucktot,
                     uint* __restrict__ epack, int* __restrict__ offs,
                     int N, int E, int B) {
    __shared__ int ps[256];
    __shared__ uint ed[P2CAP];
    __shared__ int cnt[256], off[256], cur[256];
    int b = blockIdx.x, tid = threadIdx.x;
    int bt = (tid < B) ? bucktot[tid] : 0;
    ps[tid] = bt;
    __syncthreads();
    for (int o = 1; o < 256; o <<= 1) {
        int v = (tid >= o) ? ps[tid - o] : 0;
        __syncthreads();
        ps[tid] += v;
        __syncthreads();
    }
    int j0 = ps[b] - ((b < B) ? bucktot[b] : 0);   // exclusive prefix of bucket b
    int count = ps[b] - j0;
    if (count > P2CAP) count = P2CAP;
    for (int i = tid; i < count; i += 256) ed[i] = edata[j0 + i];
    cnt[tid] = 0;
    __syncthreads();
    for (int i = tid; i < count; i += 256) atomicAdd(&cnt[(ed[i] >> 4) & 255], 1);
    __syncthreads();
    // parallel exclusive prefix of cnt -> off/cur (ps reused; j0/count in regs)
    int myc = cnt[tid];
    ps[tid] = myc;
    __syncthreads();
    for (int o = 1; o < 256; o <<= 1) {
        int v = (tid >= o) ? ps[tid - o] : 0;
        __syncthreads();
        ps[tid] += v;
        __syncthreads();
    }
    off[tid] = ps[tid] - myc;
    cur[tid] = ps[tid] - myc;
    __syncthreads();
    for (int i = tid; i < count; i += 256) {
        uint v = ed[i];
        int dl = (v >> 4) & 255;
        int r = atomicAdd(&cur[dl], 1);
        epack[j0 + r] = ((v & 15u) << 28) | (v >> 12);
    }
    int v = b * 256 + tid;
    if (v < N) offs[v] = j0 + off[tid];
    if (b == 0 && tid == 0) offs[N] = E;
}

// ---------- K3: z[v][r] = sum of y[src] over edges (dst=v, type=r) ------------
// R7 form (proven): coalesced 64-edge chunk load + shfl broadcast + 4-deep
// row gathers. (R11 switch-free = 94.7us serialized; R10 in-GEMM = 379us.)
__global__ void k_zagg(const ushort* __restrict__ ybuf, const int* __restrict__ offs,
                       const uint* __restrict__ epack, ushort* __restrict__ zbuf, int N) {
    int wave = threadIdx.x >> 6;
    int l = threadIdx.x & 63;
    int v = blockIdx.x * 4 + wave;
    if (v >= N) return;
    float2 a0 = {0.f,0.f}, a1 = {0.f,0.f}, a2 = {0.f,0.f}, a3 = {0.f,0.f};
    float2 a4 = {0.f,0.f}, a5 = {0.f,0.f}, a6 = {0.f,0.f}, a7 = {0.f,0.f};
    const uint* yb = (const uint*)ybuf;
    int j = offs[v], e1 = offs[v + 1];

#define ZACC(P, U) do {                                                   \
        float lo = bf_lo(U), hi = bf_hi(U);                               \
        switch ((P) >> 28) {                                              \
            case 0: a0.x += lo; a0.y += hi; break;                        \
            case 1: a1.x += lo; a1.y += hi; break;                        \
            case 2: a2.x += lo; a2.y += hi; break;                        \
            case 3: a3.x += lo; a3.y += hi; break;                        \
            case 4: a4.x += lo; a4.y += hi; break;                        \
            case 5: a5.x += lo; a5.y += hi; break;                        \
            case 6: a6.x += lo; a6.y += hi; break;                        \
            default: a7.x += lo; a7.y += hi; break;                       \
        }                                                                 \
    } while (0)

    while (j < e1) {
        int chunk = min(64, e1 - j);
        uint pl = (j + l < e1) ? epack[j + l] : 0;
        int i = 0;
        for (; i + 3 < chunk; i += 4) {
            uint p0 = __shfl(pl, i, 64);
            uint p1 = __shfl(pl, i + 1, 64);
            uint p2 = __shfl(pl, i + 2, 64);
            uint p3 = __shfl(pl, i + 3, 64);
            uint u0 = yb[(size_t)(p0 & 0x0FFFFFFFu) * 64 + l];
            uint u1 = yb[(size_t)(p1 & 0x0FFFFFFFu) * 64 + l];
            uint u2 = yb[(size_t)(p2 & 0x0FFFFFFFu) * 64 + l];
            uint u3 = yb[(size_t)(p3 & 0x0FFFFFFFu) * 64 + l];
            ZACC(p0, u0); ZACC(p1, u1); ZACC(p2, u2); ZACC(p3, u3);
        }
        for (; i < chunk; ++i) {
            uint p = __shfl(pl, i, 64);
            uint u = yb[(size_t)(p & 0x0FFFFFFFu) * 64 + l];
            ZACC(p, u);
        }
        j += chunk;
    }
#undef ZACC
    uint* zrow = (uint*)(zbuf + (size_t)v * 1024);
    zrow[0 * 64 + l] = ((uint)f2bf(a0.y) << 16) | f2bf(a0.x);
    zrow[1 * 64 + l] = ((uint)f2bf(a1.y) << 16) | f2bf(a1.x);
    zrow[2 * 64 + l] = ((uint)f2bf(a2.y) << 16) | f2bf(a2.x);
    zrow[3 * 64 + l] = ((uint)f2bf(a3.y) << 16) | f2bf(a3.x);
    zrow[4 * 64 + l] = ((uint)f2bf(a4.y) << 16) | f2bf(a4.x);
    zrow[5 * 64 + l] = ((uint)f2bf(a5.y) << 16) | f2bf(a5.x);
    zrow[6 * 64 + l] = ((uint)f2bf(a6.y) << 16) | f2bf(a6.x);
    zrow[7 * 64 + l] = ((uint)f2bf(a7.y) << 16) | f2bf(a7.x);
}

// ---------- K4: LDS-staged conv-GEMM (K=1152) + LN2 + ReLU + MLP --------------
// R7 form verbatim (65us, occ 23%): 32KB LDS, y2-overlay on bsm[1], zbuf input.
__device__ __forceinline__ void gl_lds16(const void* g, void* l) {
    __builtin_amdgcn_global_load_lds((const AS1 void*)g, (AS3 void*)l, 16, 0, 0);
}
__device__ __forceinline__ void stage_half(const ushort* __restrict__ Wt, int q,
                                           ushort* bsm0, int wave, int lane) {
    const char* g = (const char*)Wt + (size_t)q * 16384 + lane * 16;
    char* l = (char*)bsm0 + (q & 1) * 16384;
    #pragma unroll
    for (int i = 0; i < 4; ++i) {
        int c = i * 4 + wave;
        gl_lds16(g + c * 1024, l + c * 1024);
    }
}
__device__ __forceinline__ void stage_mlp_slice(const ushort* __restrict__ Wt, int nt,
                                                ushort* bsm0, int wave, int lane) {
    const char* g = (const char*)Wt + (size_t)(9 + wave) * 32768 + nt * 4096 + lane * 16;
    char* l = (char*)bsm0 + (nt & 1) * 16384 + wave * 4096;
    #pragma unroll
    for (int i = 0; i < 4; ++i)
        gl_lds16(g + i * 1024, l + i * 1024);
}
__device__ __forceinline__ void aloadG(short8 (&d)[4], const ushort* p, int off, int ao) {
    #pragma unroll
    for (int ks = 0; ks < 4; ++ks)
        d[ks] = *(const short8*)(p + off + ks * 32 + ao);
}
__device__ __forceinline__ void convHalf(float4v (&acc)[8], const short8 (&a)[4],
                                         const ushort* bsm_h, int h, int lane) {
    #pragma unroll
    for (int nt4 = 0; nt4 < 4; ++nt4) {
        #pragma unroll
        for (int ks = 0; ks < 4; ++ks) {
            short8 b = *(const short8*)(bsm_h + (((nt4 * 4 + ks) * 64 + lane) << 3));
            acc[h * 4 + nt4] = __builtin_amdgcn_mfma_f32_16x16x32_bf16(
                a[ks], b, acc[h * 4 + nt4], 0, 0, 0);
        }
    }
}

__launch_bounds__(256, 4)
__global__ void k_gm(const ushort* __restrict__ ybuf, const ushort* __restrict__ zbuf,
                     const ushort* __restrict__ Wt, const float* __restrict__ x,
                     const int* __restrict__ ntp,
                     const float* __restrict__ gamma, const float* __restrict__ beta,
                     const float* __restrict__ bmlp, float* __restrict__ out, int N) {
    __shared__ ushort bsm[2][8192];      // 2 x 16KB ping-pong; bsm[1] doubles as y2 overlay
    ushort* bsm0 = &bsm[0][0];
    int tid = threadIdx.x;
    int wave = tid >> 6, lane = tid & 63;
    int quad = lane >> 4, l15 = lane & 15;
    int ao = quad * 8;
    int base = blockIdx.x * 64 + wave * 16;             // 16 rows per wave

    const ushort* yrow = ybuf + (size_t)min(base + l15, N - 1) * 128;
    const ushort* zrow = zbuf + (size_t)min(base + l15, N - 1) * 1024;

    float4v acc[8];
    #pragma unroll
    for (int nt = 0; nt < 8; ++nt) acc[nt] = (float4v){0.f, 0.f, 0.f, 0.f};

    short8 aC[4], aN[4];
    stage_half(Wt, 0, bsm0, wave, lane);
    aloadG(aC, yrow, 0, ao);
    __syncthreads();

    #pragma unroll
    for (int m = 0; m < 9; ++m) {
        short8 (&cur)[4] = (m & 1) ? aN : aC;           // holds A[m]
        short8 (&nxt)[4] = (m & 1) ? aC : aN;
        stage_half(Wt, 2 * m + 1, bsm0, wave, lane);
        if (m < 8) aloadG(nxt, zrow, m * 128, ao);      // A[m+1] = z slot m
        convHalf(acc, cur, bsm0, 0, lane);
        __syncthreads();
        if (m < 8) stage_half(Wt, 2 * m + 2, bsm0, wave, lane);
        else       stage_mlp_slice(Wt, 0, bsm0, wave, lane);
        convHalf(acc, cur, bsm0 + 8192, 1, lane);
        __syncthreads();
    }

    ushort* yov = bsm0 + 8192 + wave * 2048;
    int ty[4];
    {
        float s[4] = {0.f, 0.f, 0.f, 0.f}, s2[4] = {0.f, 0.f, 0.f, 0.f};
        #pragma unroll
        for (int nt = 0; nt < 8; ++nt) {
            int col = nt * 16 + l15;
            #pragma unroll
            for (int r = 0; r < 4; ++r) {
                int row = base + quad * 4 + r;
                float xv = (row < N) ? x[(size_t)row * D + col] : 0.f;
                float t = acc[nt][r] + xv;
                acc[nt][r] = t;
                s[r] += t; s2[r] += t * t;
            }
        }
        #pragma unroll
        for (int r = 0; r < 4; ++r) {
            #pragma unroll
            for (int o = 1; o < 16; o <<= 1) {
                s[r]  += __shfl_xor(s[r],  o, 64);
                s2[r] += __shfl_xor(s2[r], o, 64);
            }
        }
        #pragma unroll
        for (int r = 0; r < 4; ++r) {
            int rc = min(base + quad * 4 + r, N - 1);
            ty[r] = ntp[rc];
            float mu  = s[r] * (1.0f / D);
            float var = s2[r] * (1.0f / D) - mu * mu;
            float inv = rsqrtf(var + EPS);
            int lrow = quad * 4 + r;
            #pragma unroll
            for (int nt = 0; nt < 8; ++nt) {
                int col = nt * 16 + l15;
                float yn = fmaxf((acc[nt][r] - mu) * inv * gamma[ty[r] * D + col]
                                 + beta[ty[r] * D + col], 0.f);
                yov[lrow * 128 + col] = f2bf(yn);
            }
        }
    }
    short8 a2[4];
    {
        const ushort* myrow = yov + l15 * 128;
        #pragma unroll
        for (int ks = 0; ks < 4; ++ks) a2[ks] = *(const short8*)(myrow + ks * 32 + ao);
    }
    __syncthreads();    // a2 settled before slice-1 staging clobbers overlay

    #pragma unroll
    for (int nt = 0; nt < 8; ++nt) {
        if (nt < 7) stage_mlp_slice(Wt, nt + 1, bsm0, wave, lane);
        const ushort* bh = bsm0 + (nt & 1) * 8192;
        float4v c0 = {0.f,0.f,0.f,0.f}, c1 = {0.f,0.f,0.f,0.f};
        float4v c2 = {0.f,0.f,0.f,0.f}, c3 = {0.f,0.f,0.f,0.f};
        #pragma unroll
        for (int ks = 0; ks < 4; ++ks) {
            int fo = (ks * 64 + lane) << 3;
            short8 b0 = *(const short8*)(bh + 0 * 2048 + fo);
            short8 b1 = *(const short8*)(bh + 1 * 2048 + fo);
            short8 b2 = *(const short8*)(bh + 2 * 2048 + fo);
            short8 b3 = *(const short8*)(bh + 3 * 2048 + fo);
            c0 = __builtin_amdgcn_mfma_f32_16x16x32_bf16(a2[ks], b0, c0, 0, 0, 0);
            c1 = __builtin_amdgcn_mfma_f32_16x16x32_bf16(a2[ks], b1, c1, 0, 0, 0);
            c2 = __builtin_amdgcn_mfma_f32_16x16x32_bf16(a2[ks], b2, c2, 0, 0, 0);
            c3 = __builtin_amdgcn_mfma_f32_16x16x32_bf16(a2[ks], b3, c3, 0, 0, 0);
        }
        int col = nt * 16 + l15;
        #pragma unroll
        for (int r = 0; r < 4; ++r) {
            int row = base + quad * 4 + r;
            if (row < N) {
                int t = ty[r];
                float v = (t == 0) ? c0[r] : (t == 1) ? c1[r] : (t == 2) ? c2[r] : c3[r];
                out[(size_t)row * D + col] = acc[nt][r] + v + bmlp[t * D + col];
            }
        }
        if (nt < 7) __syncthreads();
    }
}

// ---------- launch ------------------------------------------------------------
extern "C" void kernel_launch(void* const* d_in, const int* in_sizes, int n_in,
                              void* d_out, int out_size, void* d_ws, size_t ws_size,
                              hipStream_t stream) {
    const float* x          = (const float*)d_in[0];
    const int*   esrc       = (const int*)d_in[1];
    const int*   edst       = (const int*)d_in[2];
    const int*   ntyp       = (const int*)d_in[3];
    const int*   etyp       = (const int*)d_in[4];
    const float* conv_gamma = (const float*)d_in[5];
    const float* conv_beta  = (const float*)d_in[6];
    const float* W_rel      = (const float*)d_in[7];
    const float* W_root     = (const float*)d_in[8];
    const float* mlp_gamma  = (const float*)d_in[9];
    const float* mlp_beta   = (const float*)d_in[10];
    const float* W_mlp      = (const float*)d_in[11];
    const float* b_mlp      = (const float*)d_in[12];
    float* out = (float*)d_out;

    int N = in_sizes[0] / D;
    int E = in_sizes[1];
    int C = (E + CHK - 1) / CHK;        // chunks (<=128)
    int B = (N + 255) / 256;            // coarse buckets (<=256)

    char* p = (char*)d_ws;
    auto take = [&p](size_t bytes) { char* q = p; p += (bytes + 255) & ~(size_t)255; return q; };
    ushort* ybuf    = (ushort*)take((size_t)N * D * 2);
    ushort* zbuf    = (ushort*)take((size_t)N * 1024 * 2);
    ushort* Wt      = (ushort*)take((size_t)13 * D * D * 2);
    uint*   edata   = (uint*)take((size_t)E * 4);
    uint*   epack   = (uint*)take((size_t)E * 4);
    int*    offs    = (int*)take((size_t)(N + 1) * 4);
    int*    hist    = (int*)take((size_t)C * B * 4);
    int*    chunkoff= (int*)take((size_t)C * B * 4);
    int*    bucktot = (int*)take((size_t)B * 4);

    // K1: weights + LN1 + fused chunk-hist
    k_ln1cvt<<<13 + (N + 3) / 4, 256, 0, stream>>>(x, ntyp, conv_gamma, conv_beta,
                                                   ybuf, W_rel, W_root, W_mlp, Wt,
                                                   edst, hist, N, E, C, B);

    k_c2<<<B, 128, 0, stream>>>(hist, chunkoff, bucktot, C, B);
    k_p1s<<<C, 256, 0, stream>>>(edst, esrc, etyp, bucktot, chunkoff, edata, E, B);
    k_p2<<<B, 256, 0, stream>>>(edata, bucktot, epack, offs, N, E, B);

    k_zagg<<<(N + 3) / 4, 256, 0, stream>>>(ybuf, offs, epack, zbuf, N);

    k_gm<<<(N + 63) / 64, 256, 0, stream>>>(ybuf, zbuf, Wt, x, ntyp,
                                            mlp_gamma, mlp_beta, b_mlp, out, N);
}